// Round 1
// baseline (1358.070 us; speedup 1.0000x reference)
//
#include <hip/hip_runtime.h>
#include <hip/hip_bf16.h>

// Problem constants (B,N,C,H,D,K) = (4, 8192, 384, 12, 2, 32)
#define B_  4
#define N_  8192
#define C_  384
#define H_  12
#define D_  2
#define K_  32
#define M_  256          // N/K members per cluster
#define CH_ 16           // C/H/2
#define BN_ (B_*N_)      // 32768 rows
#define QKVD 1152        // 3*C  (per-head layout: h*96 + s*16 + c, s in 0..5)
#define F2D 768          // 2*C
// per-head spans inside the 1152-wide qkv row:
//   q: [h*96 +  0, +16)   k: [h*96 + 16, +32)   v: [h*96 + 32, +96)

// ---------------------------------------------------------------- pos max
__global__ void posmax_kernel(const float* __restrict__ pos, unsigned* __restrict__ pmax) {
    int tid = blockIdx.x * blockDim.x + threadIdx.x;
    float m0 = 0.f, m1 = 0.f;
    for (int i = tid; i < BN_; i += gridDim.x * blockDim.x) {
        m0 = fmaxf(m0, pos[(size_t)i * 2 + 0]);
        m1 = fmaxf(m1, pos[(size_t)i * 2 + 1]);
    }
    #pragma unroll
    for (int off = 32; off; off >>= 1) {
        m0 = fmaxf(m0, __shfl_down(m0, off));
        m1 = fmaxf(m1, __shfl_down(m1, off));
    }
    __shared__ float s0[4], s1[4];
    int w = threadIdx.x >> 6;
    if ((threadIdx.x & 63) == 0) { s0[w] = m0; s1[w] = m1; }
    __syncthreads();
    if (threadIdx.x == 0) {
        for (int i = 1; i < 4; i++) { m0 = fmaxf(m0, s0[i]); m1 = fmaxf(m1, s1[i]); }
        // pos >= 0 so float ordering == uint-bit ordering
        atomicMax(&pmax[0], __float_as_uint(m0));
        atomicMax(&pmax[1], __float_as_uint(m1));
    }
}

// ---------------------------------------------------------------- qkv GEMM
// qkv[m, n] = sum_k feat[m,k] * w_qkv[n,k] + b_qkv[n]   (M=32768, N=1152, K=384)
__global__ __launch_bounds__(256) void gemm_qkv(const float* __restrict__ A,
                                                const float* __restrict__ W,
                                                const float* __restrict__ bias,
                                                __hip_bfloat16* __restrict__ Cq) {
    __shared__ float As[16][64];
    __shared__ float Ws[16][64];
    const int bm = blockIdx.y * 64, bn = blockIdx.x * 64;
    const int tid = threadIdx.x, tx = tid & 15, ty = tid >> 4;
    float acc[4][4] = {};
    for (int k0 = 0; k0 < 384; k0 += 16) {
        #pragma unroll
        for (int l = 0; l < 4; l++) {
            int idx = tid + l * 256; int kk = idx & 15, m = idx >> 4;
            As[kk][m] = A[(size_t)(bm + m) * 384 + k0 + kk];
        }
        #pragma unroll
        for (int l = 0; l < 4; l++) {
            int idx = tid + l * 256; int kk = idx & 15, n = idx >> 4;
            Ws[kk][n] = W[(size_t)(bn + n) * 384 + k0 + kk];
        }
        __syncthreads();
        #pragma unroll
        for (int kk = 0; kk < 16; kk++) {
            float a[4], w[4];
            #pragma unroll
            for (int i = 0; i < 4; i++) a[i] = As[kk][ty * 4 + i];
            #pragma unroll
            for (int j = 0; j < 4; j++) w[j] = Ws[kk][tx * 4 + j];
            #pragma unroll
            for (int i = 0; i < 4; i++)
                #pragma unroll
                for (int j = 0; j < 4; j++) acc[i][j] += a[i] * w[j];
        }
        __syncthreads();
    }
    for (int i = 0; i < 4; i++) {
        size_t m = bm + ty * 4 + i;
        for (int j = 0; j < 4; j++) {
            int n = bn + tx * 4 + j;
            Cq[m * QKVD + n] = __float2bfloat16(acc[i][j] + bias[n]);
        }
    }
}

// ---------------------------------------------------------------- attention
// One block per (b, k-cluster, h). 256 threads, thread t owns member row t.
// softmax bias s[j]-s[i]+b_pos[h]: the -s[i]+b_pos part is constant over the
// softmax axis -> cancels exactly; only +s[j] is applied.
__global__ __launch_bounds__(256) void attn_kernel(const __hip_bfloat16* __restrict__ qkv,
                                                   const int* __restrict__ member_idx,
                                                   const float* __restrict__ pos,
                                                   const float* __restrict__ w_pos,
                                                   const unsigned* __restrict__ pmax_u,
                                                   __hip_bfloat16* __restrict__ feat2) {
    const int h = blockIdx.x, kc = blockIdx.y, b = blockIdx.z;
    __shared__ float Ks[M_][CH_];   // 16 KB
    __shared__ float Sp[M_];        // 1 KB
    __shared__ int   Idx[M_];       // 1 KB
    __shared__ float Vs[64][64];    // 16 KB
    const int t = threadIdx.x;
    const int* mi = member_idx + (((size_t)b * H_ + h) * K_ + kc) * M_;
    const int n = mi[t];
    Idx[t] = n;
    const float inv0 = 1.f / __uint_as_float(pmax_u[0]);
    const float inv1 = 1.f / __uint_as_float(pmax_u[1]);
    Sp[t] = pos[((size_t)b * N_ + n) * 2 + 0] * inv0 * w_pos[h * 2 + 0]
          + pos[((size_t)b * N_ + n) * 2 + 1] * inv1 * w_pos[h * 2 + 1];

    const __hip_bfloat16* base = qkv + ((size_t)b * N_ + n) * QKVD + h * 96;
    const float scale = 0.17677669529663687f;  // (C/H)^-0.5 = 1/sqrt(32)
    float q[CH_];
    #pragma unroll
    for (int c = 0; c < CH_; c++) q[c] = __bfloat162float(base[c]) * scale;
    #pragma unroll
    for (int c = 0; c < CH_; c++) Ks[t][c] = __bfloat162float(base[CH_ + c]);
    __syncthreads();

    // pass 1: row max of (q . k_j + s_j)
    float mx = -1e30f;
    for (int j = 0; j < M_; j++) {
        float s = Sp[j];
        #pragma unroll
        for (int c = 0; c < CH_; c++) s += q[c] * Ks[j][c];
        mx = fmaxf(mx, s);
    }

    // pass 2: exp + accumulate out = P @ V with V staged in 64-row tiles
    float sum = 0.f;
    float out[64];
    #pragma unroll
    for (int c = 0; c < 64; c++) out[c] = 0.f;
    for (int jt = 0; jt < M_; jt += 64) {
        __syncthreads();
        #pragma unroll
        for (int l = 0; l < 16; l++) {
            int idx = t + l * 256;             // 4096 = 64x64
            int row = idx >> 6, col = idx & 63;
            int nj = Idx[jt + row];
            Vs[row][col] = __bfloat162float(qkv[((size_t)b * N_ + nj) * QKVD + h * 96 + 32 + col]);
        }
        __syncthreads();
        for (int j = 0; j < 64; j++) {
            float s = Sp[jt + j];
            #pragma unroll
            for (int c = 0; c < CH_; c++) s += q[c] * Ks[jt + j][c];
            float p = __expf(s - mx);
            sum += p;
            #pragma unroll
            for (int c = 0; c < 64; c++) out[c] += p * Vs[j][c];
        }
    }
    const float inv = 1.f / sum;
    __hip_bfloat16* dst = feat2 + ((size_t)b * N_ + n) * F2D + h * 64;
    #pragma unroll
    for (int c = 0; c < 64; c++) dst[c] = __float2bfloat16(out[c] * inv);
}

// ---------------------------------------------------------------- proj GEMM
// out[m, n] = sum_k feat2[m,k] * w_proj[n,k] + b_proj[n]  (M=32768, N=384, K=768)
__global__ __launch_bounds__(256) void gemm_proj(const __hip_bfloat16* __restrict__ A,
                                                 const float* __restrict__ W,
                                                 const float* __restrict__ bias,
                                                 float* __restrict__ Co) {
    __shared__ float As[16][64];
    __shared__ float Ws[16][64];
    const int bm = blockIdx.y * 64, bn = blockIdx.x * 64;
    const int tid = threadIdx.x, tx = tid & 15, ty = tid >> 4;
    float acc[4][4] = {};
    for (int k0 = 0; k0 < 768; k0 += 16) {
        #pragma unroll
        for (int l = 0; l < 4; l++) {
            int idx = tid + l * 256; int kk = idx & 15, m = idx >> 4;
            As[kk][m] = __bfloat162float(A[(size_t)(bm + m) * F2D + k0 + kk]);
        }
        #pragma unroll
        for (int l = 0; l < 4; l++) {
            int idx = tid + l * 256; int kk = idx & 15, n = idx >> 4;
            Ws[kk][n] = W[(size_t)(bn + n) * F2D + k0 + kk];
        }
        __syncthreads();
        #pragma unroll
        for (int kk = 0; kk < 16; kk++) {
            float a[4], w[4];
            #pragma unroll
            for (int i = 0; i < 4; i++) a[i] = As[kk][ty * 4 + i];
            #pragma unroll
            for (int j = 0; j < 4; j++) w[j] = Ws[kk][tx * 4 + j];
            #pragma unroll
            for (int i = 0; i < 4; i++)
                #pragma unroll
                for (int j = 0; j < 4; j++) acc[i][j] += a[i] * w[j];
        }
        __syncthreads();
    }
    for (int i = 0; i < 4; i++) {
        size_t m = bm + ty * 4 + i;
        for (int j = 0; j < 4; j++) {
            int n = bn + tx * 4 + j;
            Co[m * C_ + n] = acc[i][j] + bias[n];
        }
    }
}

// ---------------------------------------------------------------- launch
extern "C" void kernel_launch(void* const* d_in, const int* in_sizes, int n_in,
                              void* d_out, int out_size, void* d_ws, size_t ws_size,
                              hipStream_t stream) {
    const float* pos    = (const float*)d_in[0];
    const float* feat   = (const float*)d_in[1];
    const int*   midx   = (const int*)  d_in[2];
    const float* w_qkv  = (const float*)d_in[3];
    const float* b_qkv  = (const float*)d_in[4];
    const float* w_pos  = (const float*)d_in[5];
    const float* b_pos  = (const float*)d_in[6];  (void)b_pos; // cancels in softmax
    const float* w_proj = (const float*)d_in[7];
    const float* b_proj = (const float*)d_in[8];
    float* out = (float*)d_out;

    // workspace layout: [pmax 8B | pad to 256 | qkv bf16 75.5MB | feat2 bf16 50.3MB]
    unsigned* pmax = (unsigned*)d_ws;
    __hip_bfloat16* qkv   = (__hip_bfloat16*)((char*)d_ws + 256);
    __hip_bfloat16* feat2 = qkv + (size_t)BN_ * QKVD;

    hipMemsetAsync(pmax, 0, 8, stream);  // ws is NOT re-poisoned between replays
    posmax_kernel<<<64, 256, 0, stream>>>(pos, pmax);
    gemm_qkv<<<dim3(QKVD / 64, BN_ / 64), 256, 0, stream>>>(feat, w_qkv, b_qkv, qkv);
    attn_kernel<<<dim3(H_, K_, B_), 256, 0, stream>>>(qkv, midx, pos, w_pos, pmax, feat2);
    gemm_proj<<<dim3(C_ / 64, BN_ / 64), 256, 0, stream>>>(feat2, w_proj, b_proj, out);
}

// Round 2
// 473.974 us; speedup vs baseline: 2.8653x; 2.8653x over previous
//
#include <hip/hip_runtime.h>
#include <hip/hip_bf16.h>

// Problem constants (B,N,C,H,D,K) = (4, 8192, 384, 12, 2, 32)
#define B_  4
#define N_  8192
#define C_  384
#define H_  12
#define D_  2
#define K_  32
#define M_  256          // N/K members per cluster
#define CH_ 16           // C/H/2
#define BN_ (B_*N_)      // 32768 rows
#define QKVD 1152        // 3*C  (per-head layout: h*96 + s*16 + c, s in 0..5)
#define F2D 768          // 2*C

typedef __attribute__((ext_vector_type(8))) short bf16x8;   // 8 bf16 (4 VGPRs)
typedef __attribute__((ext_vector_type(4))) float f32x4;    // MFMA C/D

#define GLOBAL_AS __attribute__((address_space(1)))
#define LDS_AS    __attribute__((address_space(3)))

__device__ __forceinline__ void load_lds_16B(const ushort* g, ushort* l) {
    __builtin_amdgcn_global_load_lds((const GLOBAL_AS unsigned int*)g,
                                     (LDS_AS unsigned int*)l, 16, 0, 0);
}

// ---------------------------------------------------------------- pos max
__global__ void posmax_kernel(const float* __restrict__ pos, unsigned* __restrict__ pmax) {
    int tid = blockIdx.x * blockDim.x + threadIdx.x;
    float m0 = 0.f, m1 = 0.f;
    for (int i = tid; i < BN_; i += gridDim.x * blockDim.x) {
        m0 = fmaxf(m0, pos[(size_t)i * 2 + 0]);
        m1 = fmaxf(m1, pos[(size_t)i * 2 + 1]);
    }
    #pragma unroll
    for (int off = 32; off; off >>= 1) {
        m0 = fmaxf(m0, __shfl_down(m0, off));
        m1 = fmaxf(m1, __shfl_down(m1, off));
    }
    __shared__ float s0[4], s1[4];
    int w = threadIdx.x >> 6;
    if ((threadIdx.x & 63) == 0) { s0[w] = m0; s1[w] = m1; }
    __syncthreads();
    if (threadIdx.x == 0) {
        for (int i = 1; i < 4; i++) { m0 = fmaxf(m0, s0[i]); m1 = fmaxf(m1, s1[i]); }
        atomicMax(&pmax[0], __float_as_uint(m0));   // pos >= 0: float order == uint order
        atomicMax(&pmax[1], __float_as_uint(m1));
    }
}

// ---------------------------------------------------------------- f32 -> bf16 cast
__global__ __launch_bounds__(256) void cast_kernel(const float* __restrict__ src,
                                                   ushort* __restrict__ dst, int n4) {
    int i = blockIdx.x * blockDim.x + threadIdx.x;
    if (i >= n4) return;
    float4 a = reinterpret_cast<const float4*>(src)[i];
    ushort4 o;
    __hip_bfloat16 h0 = __float2bfloat16(a.x); o.x = *(const ushort*)&h0;
    __hip_bfloat16 h1 = __float2bfloat16(a.y); o.y = *(const ushort*)&h1;
    __hip_bfloat16 h2 = __float2bfloat16(a.z); o.z = *(const ushort*)&h2;
    __hip_bfloat16 h3 = __float2bfloat16(a.w); o.w = *(const ushort*)&h3;
    reinterpret_cast<ushort4*>(dst)[i] = o;
}

// ---------------------------------------------------------------- MFMA GEMM
// C[m,n] = sum_k A[m,k]*Bw[n,k] + bias[n].  A:[M][Kdim] bf16, Bw:[Ndim][Kdim] bf16.
// 128x128 tile, BK=64, 4 waves in 2x2, each wave 64x64 via 4x4 16x16x32 frags.
template<int Kdim, int Ndim, bool OUT_BF16>
__global__ __launch_bounds__(256) void gemm_mfma(const ushort* __restrict__ A,
                                                 const ushort* __restrict__ Bw,
                                                 const float* __restrict__ bias,
                                                 void* __restrict__ Cout) {
    __shared__ ushort As[128 * 64];   // 16 KB, row-major [row][k]
    __shared__ ushort Bs[128 * 64];   // 16 KB, [n][k]
    const int bm = blockIdx.y * 128, bn = blockIdx.x * 128;
    const int t = threadIdx.x;
    const int l = t & 63;
    const int wr = (t >> 6) >> 1, wc = (t >> 6) & 1;    // 2x2 wave grid
    const int fr = l & 15, fq = l >> 4;                 // fragment row sel / k-group

    f32x4 zero = {0.f, 0.f, 0.f, 0.f};
    f32x4 acc[4][4];
    #pragma unroll
    for (int m = 0; m < 4; m++)
        #pragma unroll
        for (int n = 0; n < 4; n++) acc[m][n] = zero;

    for (int k0 = 0; k0 < Kdim; k0 += 64) {
        #pragma unroll
        for (int i = 0; i < 4; i++) {                   // A tile: 128x64 bf16, 16B/lane
            int elem = (i * 256 + t) * 8;
            int row = elem >> 6, kk = elem & 63;
            load_lds_16B(A + (size_t)(bm + row) * Kdim + k0 + kk, &As[elem]);
        }
        #pragma unroll
        for (int i = 0; i < 4; i++) {                   // B tile
            int elem = (i * 256 + t) * 8;
            int row = elem >> 6, kk = elem & 63;
            load_lds_16B(Bw + (size_t)(bn + row) * Kdim + k0 + kk, &Bs[elem]);
        }
        __syncthreads();                                // drains vmcnt before LDS reads
        #pragma unroll
        for (int kk = 0; kk < 64; kk += 32) {
            bf16x8 af[4], bfr[4];
            #pragma unroll
            for (int m = 0; m < 4; m++)
                af[m] = *reinterpret_cast<const bf16x8*>(&As[(wr * 64 + m * 16 + fr) * 64 + kk + fq * 8]);
            #pragma unroll
            for (int n = 0; n < 4; n++)
                bfr[n] = *reinterpret_cast<const bf16x8*>(&Bs[(wc * 64 + n * 16 + fr) * 64 + kk + fq * 8]);
            #pragma unroll
            for (int m = 0; m < 4; m++)
                #pragma unroll
                for (int n = 0; n < 4; n++)
                    acc[m][n] = __builtin_amdgcn_mfma_f32_16x16x32_bf16(af[m], bfr[n], acc[m][n], 0, 0, 0);
        }
        __syncthreads();
    }
    // epilogue: C/D layout col = lane&15, row = (lane>>4)*4 + reg
    #pragma unroll
    for (int n = 0; n < 4; n++) {
        int col = bn + wc * 64 + n * 16 + fr;
        float bc = bias[col];
        #pragma unroll
        for (int m = 0; m < 4; m++) {
            #pragma unroll
            for (int r = 0; r < 4; r++) {
                size_t row = bm + wr * 64 + m * 16 + fq * 4 + r;
                float v = acc[m][n][r] + bc;
                if (OUT_BF16) {
                    __hip_bfloat16 hv = __float2bfloat16(v);
                    ((ushort*)Cout)[row * Ndim + col] = *(const ushort*)&hv;
                } else {
                    ((float*)Cout)[row * Ndim + col] = v;
                }
            }
        }
    }
}

// ---------------------------------------------------------------- attention
// One block per (b, k-cluster, h). 256 threads, thread t owns member row t.
// bias s[j]-s[i]+b_pos[h]: -s[i]+b_pos is softmax-constant -> cancels.
__global__ __launch_bounds__(256) void attn_kernel(const __hip_bfloat16* __restrict__ qkv,
                                                   const int* __restrict__ member_idx,
                                                   const float* __restrict__ pos,
                                                   const float* __restrict__ w_pos,
                                                   const unsigned* __restrict__ pmax_u,
                                                   __hip_bfloat16* __restrict__ feat2) {
    const int h = blockIdx.x, kc = blockIdx.y, b = blockIdx.z;
    __shared__ float Ks[M_][CH_];   // 16 KB
    __shared__ float Sp[M_];        // 1 KB
    __shared__ int   Idx[M_];       // 1 KB
    __shared__ float Vs[64][64];    // 16 KB
    const int t = threadIdx.x;
    const int* mi = member_idx + (((size_t)b * H_ + h) * K_ + kc) * M_;
    const int n = mi[t];
    Idx[t] = n;
    const float inv0 = 1.f / __uint_as_float(pmax_u[0]);
    const float inv1 = 1.f / __uint_as_float(pmax_u[1]);
    Sp[t] = pos[((size_t)b * N_ + n) * 2 + 0] * inv0 * w_pos[h * 2 + 0]
          + pos[((size_t)b * N_ + n) * 2 + 1] * inv1 * w_pos[h * 2 + 1];

    const __hip_bfloat16* base = qkv + ((size_t)b * N_ + n) * QKVD + h * 96;
    const float scale = 0.17677669529663687f;  // 1/sqrt(32)
    float q[CH_];
    #pragma unroll
    for (int c = 0; c < CH_; c++) q[c] = __bfloat162float(base[c]) * scale;
    #pragma unroll
    for (int c = 0; c < CH_; c++) Ks[t][c] = __bfloat162float(base[CH_ + c]);
    __syncthreads();

    float mx = -1e30f;
    for (int j = 0; j < M_; j++) {
        float s = Sp[j];
        #pragma unroll
        for (int c = 0; c < CH_; c++) s += q[c] * Ks[j][c];
        mx = fmaxf(mx, s);
    }

    float sum = 0.f;
    float out[64];
    #pragma unroll
    for (int c = 0; c < 64; c++) out[c] = 0.f;
    for (int jt = 0; jt < M_; jt += 64) {
        __syncthreads();
        #pragma unroll
        for (int l = 0; l < 16; l++) {
            int idx = t + l * 256;             // 4096 = 64x64
            int row = idx >> 6, col = idx & 63;
            int nj = Idx[jt + row];
            Vs[row][col] = __bfloat162float(qkv[((size_t)b * N_ + nj) * QKVD + h * 96 + 32 + col]);
        }
        __syncthreads();
        for (int j = 0; j < 64; j++) {
            float s = Sp[jt + j];
            #pragma unroll
            for (int c = 0; c < CH_; c++) s += q[c] * Ks[jt + j][c];
            float p = __expf(s - mx);
            sum += p;
            #pragma unroll
            for (int c = 0; c < 64; c++) out[c] += p * Vs[j][c];
        }
    }
    const float inv = 1.f / sum;
    __hip_bfloat16* dst = feat2 + ((size_t)b * N_ + n) * F2D + h * 64;
    #pragma unroll
    for (int c = 0; c < 64; c++) dst[c] = __float2bfloat16(out[c] * inv);
}

// ---------------------------------------------------------------- launch
extern "C" void kernel_launch(void* const* d_in, const int* in_sizes, int n_in,
                              void* d_out, int out_size, void* d_ws, size_t ws_size,
                              hipStream_t stream) {
    const float* pos    = (const float*)d_in[0];
    const float* feat   = (const float*)d_in[1];
    const int*   midx   = (const int*)  d_in[2];
    const float* w_qkv  = (const float*)d_in[3];
    const float* b_qkv  = (const float*)d_in[4];
    const float* w_pos  = (const float*)d_in[5];
    const float* b_pos  = (const float*)d_in[6];  (void)b_pos; // cancels in softmax
    const float* w_proj = (const float*)d_in[7];
    const float* b_proj = (const float*)d_in[8];
    float* out = (float*)d_out;

    // workspace layout (stream-ordered reuse):
    //   [pmax 256B | qkv bf16 75.5MB | wproj_bf16 0.6MB |
    //    REGION: {feat_bf16 25.2MB + wqkv_bf16 0.9MB} then reused as feat2 50.3MB]
    char* ws = (char*)d_ws;
    unsigned* pmax  = (unsigned*)ws;
    ushort*   qkv   = (ushort*)(ws + 256);
    ushort*   wproj = (ushort*)(ws + 256 + 75497472);
    char*     region = ws + 256 + 75497472 + 589824;
    ushort*   featb = (ushort*)region;
    ushort*   wqkvb = (ushort*)(region + 25165824);
    ushort*   feat2 = (ushort*)region;   // overwrites featb/wqkvb after gemm_qkv

    hipMemsetAsync(pmax, 0, 8, stream);  // ws is NOT re-poisoned between replays
    posmax_kernel<<<64, 256, 0, stream>>>(pos, pmax);
    cast_kernel<<<(BN_ * C_ / 4 + 255) / 256, 256, 0, stream>>>(feat, featb, BN_ * C_ / 4);
    cast_kernel<<<(QKVD * C_ / 4 + 255) / 256, 256, 0, stream>>>(w_qkv, wqkvb, QKVD * C_ / 4);
    cast_kernel<<<(C_ * F2D / 4 + 255) / 256, 256, 0, stream>>>(w_proj, wproj, C_ * F2D / 4);
    gemm_mfma<384, QKVD, true><<<dim3(QKVD / 128, BN_ / 128), 256, 0, stream>>>(featb, wqkvb, b_qkv, qkv);
    attn_kernel<<<dim3(H_, K_, B_), 256, 0, stream>>>((const __hip_bfloat16*)qkv, midx, pos, w_pos, pmax,
                                                      (__hip_bfloat16*)feat2);
    gemm_mfma<768, C_, false><<<dim3(C_ / 128, BN_ / 128), 256, 0, stream>>>(feat2, wproj, b_proj, out);
}

// Round 4
// 187.110 us; speedup vs baseline: 7.2581x; 2.5331x over previous
//
#include <hip/hip_runtime.h>
#include <hip/hip_bf16.h>

// Problem constants (B,N,C,H,D,K) = (4, 8192, 384, 12, 2, 32)
#define B_  4
#define N_  8192
#define C_  384
#define H_  12
#define K_  32
#define M_  256          // N/K members per cluster
#define BN_ (B_*N_)      // 32768 rows
#define QKVD 1152        // 3*C  (per-head layout: h*96 + s*16 + c, s in 0..5)
#define F2D 768          // 2*C
#define VSTR 260         // Vt row stride in elems (520B): word-stride 130 == 2 mod 32 -> 2-way (free)

typedef __attribute__((ext_vector_type(8)))  short  bf16x8;
typedef __attribute__((ext_vector_type(4)))  float  f32x4;
typedef __attribute__((ext_vector_type(16))) float  f32x16;
typedef __attribute__((ext_vector_type(4)))  ushort ushort4v;
typedef __attribute__((ext_vector_type(8)))  ushort ushort8v;

#define GLOBAL_AS __attribute__((address_space(1)))
#define LDS_AS    __attribute__((address_space(3)))

__device__ __forceinline__ void load_lds_16B(const ushort* g, ushort* l) {
    __builtin_amdgcn_global_load_lds((const GLOBAL_AS unsigned int*)g,
                                     (LDS_AS unsigned int*)l, 16, 0, 0);
}
__device__ __forceinline__ unsigned cvtpk_bf16(float lo, float hi) {
    unsigned r;
    asm("v_cvt_pk_bf16_f32 %0, %1, %2" : "=v"(r) : "v"(lo), "v"(hi));
    return r;
}

// ---------------------------------------------------------------- pos max
__global__ void posmax_kernel(const float* __restrict__ pos, unsigned* __restrict__ pmax) {
    int tid = blockIdx.x * blockDim.x + threadIdx.x;
    float m0 = 0.f, m1 = 0.f;
    for (int i = tid; i < BN_; i += gridDim.x * blockDim.x) {
        m0 = fmaxf(m0, pos[(size_t)i * 2 + 0]);
        m1 = fmaxf(m1, pos[(size_t)i * 2 + 1]);
    }
    #pragma unroll
    for (int off = 32; off; off >>= 1) {
        m0 = fmaxf(m0, __shfl_down(m0, off));
        m1 = fmaxf(m1, __shfl_down(m1, off));
    }
    __shared__ float s0[4], s1[4];
    int w = threadIdx.x >> 6;
    if ((threadIdx.x & 63) == 0) { s0[w] = m0; s1[w] = m1; }
    __syncthreads();
    if (threadIdx.x == 0) {
        for (int i = 1; i < 4; i++) { m0 = fmaxf(m0, s0[i]); m1 = fmaxf(m1, s1[i]); }
        atomicMax(&pmax[0], __float_as_uint(m0));   // pos >= 0: float order == uint order
        atomicMax(&pmax[1], __float_as_uint(m1));
    }
}

// ---------------------------------------------------------------- f32 -> bf16 cast
__global__ __launch_bounds__(256) void cast_kernel(const float* __restrict__ src,
                                                   ushort* __restrict__ dst, int n4) {
    int i = blockIdx.x * blockDim.x + threadIdx.x;
    if (i >= n4) return;
    float4 a = reinterpret_cast<const float4*>(src)[i];
    ushort4 o;
    __hip_bfloat16 h0 = __float2bfloat16(a.x); o.x = *(const ushort*)&h0;
    __hip_bfloat16 h1 = __float2bfloat16(a.y); o.y = *(const ushort*)&h1;
    __hip_bfloat16 h2 = __float2bfloat16(a.z); o.z = *(const ushort*)&h2;
    __hip_bfloat16 h3 = __float2bfloat16(a.w); o.w = *(const ushort*)&h3;
    reinterpret_cast<ushort4*>(dst)[i] = o;
}

// ---------------------------------------------------------------- MFMA GEMM (128x128, BK=64)
template<int Kdim, int Ndim, bool OUT_BF16>
__global__ __launch_bounds__(256) void gemm_mfma(const ushort* __restrict__ A,
                                                 const ushort* __restrict__ Bw,
                                                 const float* __restrict__ bias,
                                                 void* __restrict__ Cout) {
    __shared__ ushort As[128 * 64];
    __shared__ ushort Bs[128 * 64];
    const int bm = blockIdx.y * 128, bn = blockIdx.x * 128;
    const int t = threadIdx.x;
    const int l = t & 63;
    const int wr = (t >> 6) >> 1, wc = (t >> 6) & 1;
    const int fr = l & 15, fq = l >> 4;

    f32x4 zero = {0.f, 0.f, 0.f, 0.f};
    f32x4 acc[4][4];
    #pragma unroll
    for (int m = 0; m < 4; m++)
        #pragma unroll
        for (int n = 0; n < 4; n++) acc[m][n] = zero;

    for (int k0 = 0; k0 < Kdim; k0 += 64) {
        #pragma unroll
        for (int i = 0; i < 4; i++) {
            int elem = (i * 256 + t) * 8;
            int row = elem >> 6, kk = elem & 63;
            load_lds_16B(A + (size_t)(bm + row) * Kdim + k0 + kk, &As[elem]);
        }
        #pragma unroll
        for (int i = 0; i < 4; i++) {
            int elem = (i * 256 + t) * 8;
            int row = elem >> 6, kk = elem & 63;
            load_lds_16B(Bw + (size_t)(bn + row) * Kdim + k0 + kk, &Bs[elem]);
        }
        __syncthreads();
        #pragma unroll
        for (int kk = 0; kk < 64; kk += 32) {
            bf16x8 af[4], bfr[4];
            #pragma unroll
            for (int m = 0; m < 4; m++)
                af[m] = *reinterpret_cast<const bf16x8*>(&As[(wr * 64 + m * 16 + fr) * 64 + kk + fq * 8]);
            #pragma unroll
            for (int n = 0; n < 4; n++)
                bfr[n] = *reinterpret_cast<const bf16x8*>(&Bs[(wc * 64 + n * 16 + fr) * 64 + kk + fq * 8]);
            #pragma unroll
            for (int m = 0; m < 4; m++)
                #pragma unroll
                for (int n = 0; n < 4; n++)
                    acc[m][n] = __builtin_amdgcn_mfma_f32_16x16x32_bf16(af[m], bfr[n], acc[m][n], 0, 0, 0);
        }
        __syncthreads();
    }
    #pragma unroll
    for (int n = 0; n < 4; n++) {
        int col = bn + wc * 64 + n * 16 + fr;
        float bc = bias[col];
        #pragma unroll
        for (int m = 0; m < 4; m++) {
            #pragma unroll
            for (int r = 0; r < 4; r++) {
                size_t row = bm + wr * 64 + m * 16 + fq * 4 + r;
                float v = acc[m][n][r] + bc;
                if (OUT_BF16) {
                    __hip_bfloat16 hv = __float2bfloat16(v);
                    ((ushort*)Cout)[row * Ndim + col] = *(const ushort*)&hv;
                } else {
                    ((float*)Cout)[row * Ndim + col] = v;
                }
            }
        }
    }
}

// ---------------------------------------------------------------- MFMA attention
// One block per (b,kc,h), 512 threads = 8 waves; wave w owns query rows 32w..32w+31.
// Swapped QK^T: S'[j][i] = K·Q^T so each lane holds a full j-row for one query i.
// C/D layout (32x32): col = lane&31, row = (r&3) + 8*(r>>2) + 4*(lane>>5).
__global__ __launch_bounds__(512, 2) void attn_kernel(const ushort* __restrict__ qkv,
                                                      const int* __restrict__ member_idx,
                                                      const float* __restrict__ pos,
                                                      const float* __restrict__ w_pos,
                                                      const unsigned* __restrict__ pmax_u,
                                                      ushort* __restrict__ feat2) {
    const int h = blockIdx.x, kc = blockIdx.y, b = blockIdx.z;
    __shared__ ushort Ks[M_ * 16];        // 8 KB  row-major [256][16]
    __shared__ ushort Vt[64 * VSTR];      // 32.5 KB transposed V [c][j], stride 260
    __shared__ float  SpA[M_];            // bias reordered to crow order
    __shared__ int    Idx[M_];
    __shared__ float  dinvS[8 * 32];

    const int t  = threadIdx.x;
    const int w  = t >> 6, l = t & 63;
    const int hi = l >> 5, ln = l & 31;
    const int* mi = member_idx + (((size_t)b * H_ + h) * K_ + kc) * M_;
    const size_t rowbase = (size_t)b * N_;
    const float scale = 0.17677669529663687f;   // (C/H)^-0.5 = 1/sqrt(32)

    // ---- stage bias + Idx (crow-reordered so softmax reads are consecutive broadcasts)
    if (t < M_) {
        int n = mi[t];
        Idx[t] = n;
        float inv0 = 1.f / __uint_as_float(pmax_u[0]);
        float inv1 = 1.f / __uint_as_float(pmax_u[1]);
        float sp = pos[(rowbase + n) * 2 + 0] * inv0 * w_pos[h * 2 + 0]
                 + pos[(rowbase + n) * 2 + 1] * inv1 * w_pos[h * 2 + 1];
        int jj = t & 31, jt = t >> 5;
        int r  = (jj & 3) | ((jj >> 3) << 2);
        int hb = (jj >> 2) & 1;
        SpA[jt * 32 + hb * 16 + r] = sp;
    }
    // ---- stage K rows via global_load_lds (per-lane gather source, linear LDS dest)
    {
        int row = t >> 1, half = t & 1;
        int n = mi[row];
        load_lds_16B(qkv + (rowbase + n) * QKVD + h * 96 + 16 + half * 8, &Ks[t * 8]);
    }
    // ---- stage V transposed: thread = (row-pair u, c-quarter cq); pack 2 rows per b32 write
    {
        int u = t >> 2, cq = t & 3;
        int n0 = mi[2 * u], n1 = mi[2 * u + 1];
        const ushort* s0 = qkv + (rowbase + n0) * QKVD + h * 96 + 32 + cq * 16;
        const ushort* s1 = qkv + (rowbase + n1) * QKVD + h * 96 + 32 + cq * 16;
        ushort8v v0a = *(const ushort8v*)s0;
        ushort8v v0b = *(const ushort8v*)(s0 + 8);
        ushort8v v1a = *(const ushort8v*)s1;
        ushort8v v1b = *(const ushort8v*)(s1 + 8);
        #pragma unroll
        for (int i = 0; i < 8; i++) {
            int c0 = cq * 16 + i, c1 = cq * 16 + 8 + i;
            *(unsigned*)&Vt[c0 * VSTR + 2 * u] = (unsigned)(ushort)v0a[i] | ((unsigned)(ushort)v1a[i] << 16);
            *(unsigned*)&Vt[c1 * VSTR + 2 * u] = (unsigned)(ushort)v0b[i] | ((unsigned)(ushort)v1b[i] << 16);
        }
    }
    __syncthreads();

    // ---- Q B-frag direct from global: lane needs Q[i=32w+ln][8*hi..+8]
    const int iq = 32 * w + ln;
    const int nq = Idx[iq];
    bf16x8 qf = *(const bf16x8*)(qkv + (rowbase + nq) * QKVD + h * 96 + hi * 8);

    // ---- QK^T: 8 j-tiles of 32x32
    f32x16 zero16;
    #pragma unroll
    for (int i = 0; i < 16; i++) zero16[i] = 0.f;
    f32x16 sac[8];
    #pragma unroll
    for (int jt = 0; jt < 8; jt++) {
        bf16x8 kf = *(const bf16x8*)&Ks[(32 * jt + ln) * 16 + hi * 8];
        sac[jt] = __builtin_amdgcn_mfma_f32_32x32x16_bf16(kf, qf, zero16, 0, 0, 0);
    }

    // ---- softmax (lane-local over 128 regs + one cross-half exchange)
    float mx = -3.0e38f;
    #pragma unroll
    for (int jt = 0; jt < 8; jt++) {
        f32x4 bia[4];
        #pragma unroll
        for (int q4 = 0; q4 < 4; q4++)
            bia[q4] = *(const f32x4*)&SpA[jt * 32 + hi * 16 + q4 * 4];
        #pragma unroll
        for (int r = 0; r < 16; r++) {
            float v = fmaf(sac[jt][r], scale, bia[r >> 2][r & 3]);
            sac[jt][r] = v;
            mx = fmaxf(mx, v);
        }
    }
    mx = fmaxf(mx, __shfl_xor(mx, 32));
    float sum = 0.f;
    #pragma unroll
    for (int jt = 0; jt < 8; jt++)
        #pragma unroll
        for (int r = 0; r < 16; r++) {
            float p = __expf(sac[jt][r] - mx);
            sac[jt][r] = p;
            sum += p;
        }
    sum += __shfl_xor(sum, 32);
    float inv = 1.f / sum;
    if (hi == 0) dinvS[w * 32 + ln] = inv;

    // ---- PV: O[i][c] = sum_j P[j][i] V[j][c]; A-frag built in-register via cvt_pk+permlane
    f32x16 oa0 = zero16, oa1 = zero16;
    #pragma unroll
    for (int g = 0; g < 16; g++) {
        const int jt = g >> 1, hf = (g & 1) * 8;
        unsigned a0 = cvtpk_bf16(sac[jt][hf + 0], sac[jt][hf + 1]);
        unsigned a1 = cvtpk_bf16(sac[jt][hf + 2], sac[jt][hf + 3]);
        unsigned b0 = cvtpk_bf16(sac[jt][hf + 4], sac[jt][hf + 5]);
        unsigned b1 = cvtpk_bf16(sac[jt][hf + 6], sac[jt][hf + 7]);
        asm("v_permlane32_swap_b32 %0, %1" : "+v"(a0), "+v"(b0));
        asm("v_permlane32_swap_b32 %0, %1" : "+v"(a1), "+v"(b1));
        union { unsigned u[4]; bf16x8 v; } pa;
        pa.u[0] = a0; pa.u[1] = a1; pa.u[2] = b0; pa.u[3] = b1;
        union { ushort4v h[2]; bf16x8 v; } vf0, vf1;
        vf0.h[0] = *(const ushort4v*)&Vt[ln * VSTR + g * 16 + hi * 8];
        vf0.h[1] = *(const ushort4v*)&Vt[ln * VSTR + g * 16 + hi * 8 + 4];
        vf1.h[0] = *(const ushort4v*)&Vt[(ln + 32) * VSTR + g * 16 + hi * 8];
        vf1.h[1] = *(const ushort4v*)&Vt[(ln + 32) * VSTR + g * 16 + hi * 8 + 4];
        oa0 = __builtin_amdgcn_mfma_f32_32x32x16_bf16(pa.v, vf0.v, oa0, 0, 0, 0);
        oa1 = __builtin_amdgcn_mfma_f32_32x32x16_bf16(pa.v, vf1.v, oa1, 0, 0, 0);
    }

    // ---- epilogue: lane holds O[i=crow(r,hi)][c=ln(+32)]; scatter bf16 rows
    #pragma unroll
    for (int r = 0; r < 16; r++) {
        int crow = (r & 3) + 8 * (r >> 2) + 4 * hi;
        float dv = dinvS[w * 32 + crow];
        int ni = Idx[32 * w + crow];
        __hip_bfloat16 o0 = __float2bfloat16(oa0[r] * dv);
        __hip_bfloat16 o1 = __float2bfloat16(oa1[r] * dv);
        ushort* dst = feat2 + (rowbase + ni) * F2D + h * 64 + ln;
        dst[0]  = *(const ushort*)&o0;
        dst[32] = *(const ushort*)&o1;
    }
}

// ---------------------------------------------------------------- launch
extern "C" void kernel_launch(void* const* d_in, const int* in_sizes, int n_in,
                              void* d_out, int out_size, void* d_ws, size_t ws_size,
                              hipStream_t stream) {
    const float* pos    = (const float*)d_in[0];
    const float* feat   = (const float*)d_in[1];
    const int*   midx   = (const int*)  d_in[2];
    const float* w_qkv  = (const float*)d_in[3];
    const float* b_qkv  = (const float*)d_in[4];
    const float* w_pos  = (const float*)d_in[5];
    const float* b_pos  = (const float*)d_in[6];  (void)b_pos; // cancels in softmax
    const float* w_proj = (const float*)d_in[7];
    const float* b_proj = (const float*)d_in[8];
    float* out = (float*)d_out;

    // workspace: [pmax 256B | qkv bf16 75.5MB | wproj_bf16 0.6MB |
    //             REGION: {feat_bf16 25.2MB + wqkv_bf16 0.9MB} reused as feat2 50.3MB]
    char* ws = (char*)d_ws;
    unsigned* pmax  = (unsigned*)ws;
    ushort*   qkv   = (ushort*)(ws + 256);
    ushort*   wproj = (ushort*)(ws + 256 + 75497472);
    char*     region = ws + 256 + 75497472 + 589824;
    ushort*   featb = (ushort*)region;
    ushort*   wqkvb = (ushort*)(region + 25165824);
    ushort*   feat2 = (ushort*)region;   // overwrites featb/wqkvb after gemm_qkv

    hipMemsetAsync(pmax, 0, 8, stream);  // ws is NOT re-poisoned between replays
    posmax_kernel<<<64, 256, 0, stream>>>(pos, pmax);
    cast_kernel<<<(BN_ * C_ / 4 + 255) / 256, 256, 0, stream>>>(feat, featb, BN_ * C_ / 4);
    cast_kernel<<<(QKVD * C_ / 4 + 255) / 256, 256, 0, stream>>>(w_qkv, wqkvb, QKVD * C_ / 4);
    cast_kernel<<<(C_ * F2D / 4 + 255) / 256, 256, 0, stream>>>(w_proj, wproj, C_ * F2D / 4);
    gemm_mfma<384, QKVD, true><<<dim3(QKVD / 128, BN_ / 128), 256, 0, stream>>>(featb, wqkvb, b_qkv, qkv);
    attn_kernel<<<dim3(H_, K_, B_), 512, 0, stream>>>(qkv, midx, pos, w_pos, pmax, feat2);
    gemm_mfma<768, C_, false><<<dim3(C_ / 128, BN_ / 128), 256, 0, stream>>>(feat2, wproj, b_proj, out);
}

// Round 5
// 175.202 us; speedup vs baseline: 7.7514x; 1.0680x over previous
//
#include <hip/hip_runtime.h>
#include <hip/hip_bf16.h>

// Problem constants (B,N,C,H,D,K) = (4, 8192, 384, 12, 2, 32)
#define B_  4
#define N_  8192
#define C_  384
#define H_  12
#define K_  32
#define M_  256          // N/K members per cluster
#define BN_ (B_*N_)      // 32768 rows
#define QKVD 1152        // 3*C  (per-head layout: h*96 + s*16 + c, s in 0..5)
#define F2D 768          // 2*C
#define VSTR 260         // Vt row stride in elems (520B): word-stride 130 == 2 mod 32 -> 2-way (free)

typedef __attribute__((ext_vector_type(8)))  short  bf16x8;
typedef __attribute__((ext_vector_type(4)))  float  f32x4;
typedef __attribute__((ext_vector_type(16))) float  f32x16;
typedef __attribute__((ext_vector_type(4)))  ushort ushort4v;
typedef __attribute__((ext_vector_type(8)))  ushort ushort8v;

#define GLOBAL_AS __attribute__((address_space(1)))
#define LDS_AS    __attribute__((address_space(3)))

__device__ __forceinline__ void load_lds_16B(const ushort* g, ushort* l) {
    __builtin_amdgcn_global_load_lds((const GLOBAL_AS unsigned int*)g,
                                     (LDS_AS unsigned int*)l, 16, 0, 0);
}
__device__ __forceinline__ unsigned cvtpk_bf16(float lo, float hi) {
    unsigned r;
    asm("v_cvt_pk_bf16_f32 %0, %1, %2" : "=v"(r) : "v"(lo), "v"(hi));
    return r;
}

// ---------------------------------------------------------------- pos max
__global__ void posmax_kernel(const float* __restrict__ pos, unsigned* __restrict__ pmax) {
    int tid = blockIdx.x * blockDim.x + threadIdx.x;
    float m0 = 0.f, m1 = 0.f;
    for (int i = tid; i < BN_; i += gridDim.x * blockDim.x) {
        m0 = fmaxf(m0, pos[(size_t)i * 2 + 0]);
        m1 = fmaxf(m1, pos[(size_t)i * 2 + 1]);
    }
    #pragma unroll
    for (int off = 32; off; off >>= 1) {
        m0 = fmaxf(m0, __shfl_down(m0, off));
        m1 = fmaxf(m1, __shfl_down(m1, off));
    }
    __shared__ float s0[4], s1[4];
    int w = threadIdx.x >> 6;
    if ((threadIdx.x & 63) == 0) { s0[w] = m0; s1[w] = m1; }
    __syncthreads();
    if (threadIdx.x == 0) {
        for (int i = 1; i < 4; i++) { m0 = fmaxf(m0, s0[i]); m1 = fmaxf(m1, s1[i]); }
        atomicMax(&pmax[0], __float_as_uint(m0));   // pos >= 0: float order == uint order
        atomicMax(&pmax[1], __float_as_uint(m1));
    }
}

// ---------------------------------------------------------------- f32 -> bf16 cast
__global__ __launch_bounds__(256) void cast_kernel(const float* __restrict__ src,
                                                   ushort* __restrict__ dst, int n4) {
    int i = blockIdx.x * blockDim.x + threadIdx.x;
    if (i >= n4) return;
    float4 a = reinterpret_cast<const float4*>(src)[i];
    ushort4 o;
    __hip_bfloat16 h0 = __float2bfloat16(a.x); o.x = *(const ushort*)&h0;
    __hip_bfloat16 h1 = __float2bfloat16(a.y); o.y = *(const ushort*)&h1;
    __hip_bfloat16 h2 = __float2bfloat16(a.z); o.z = *(const ushort*)&h2;
    __hip_bfloat16 h3 = __float2bfloat16(a.w); o.w = *(const ushort*)&h3;
    reinterpret_cast<ushort4*>(dst)[i] = o;
}

// ---------------------------------------------------------------- MFMA GEMM (128x128, BK=64)
// 1-D grid with XCD-aware remap: blocks on XCD x (= wgid & 7, HW round-robin) cover
// A-row strips [x*32, x*32+32) across all column blocks -> per-XCD L2 holds one A slice.
template<int Kdim, int Ndim, bool OUT_BF16>
__global__ __launch_bounds__(256) void gemm_mfma(const ushort* __restrict__ A,
                                                 const ushort* __restrict__ Bw,
                                                 const float* __restrict__ bias,
                                                 void* __restrict__ Cout) {
    constexpr int NB = Ndim / 128;            // column blocks
    __shared__ ushort As[128 * 64];
    __shared__ ushort Bs[128 * 64];
    const int wgid = blockIdx.x;
    const int xcd  = wgid & 7;
    const int loc  = wgid >> 3;               // [0, NB*32)
    const int bm = (xcd * 32 + loc / NB) * 128;
    const int bn = (loc % NB) * 128;
    const int t = threadIdx.x;
    const int l = t & 63;
    const int wr = (t >> 6) >> 1, wc = (t >> 6) & 1;
    const int fr = l & 15, fq = l >> 4;

    f32x4 zero = {0.f, 0.f, 0.f, 0.f};
    f32x4 acc[4][4];
    #pragma unroll
    for (int m = 0; m < 4; m++)
        #pragma unroll
        for (int n = 0; n < 4; n++) acc[m][n] = zero;

    for (int k0 = 0; k0 < Kdim; k0 += 64) {
        #pragma unroll
        for (int i = 0; i < 4; i++) {
            int elem = (i * 256 + t) * 8;
            int row = elem >> 6, kk = elem & 63;
            load_lds_16B(A + (size_t)(bm + row) * Kdim + k0 + kk, &As[elem]);
        }
        #pragma unroll
        for (int i = 0; i < 4; i++) {
            int elem = (i * 256 + t) * 8;
            int row = elem >> 6, kk = elem & 63;
            load_lds_16B(Bw + (size_t)(bn + row) * Kdim + k0 + kk, &Bs[elem]);
        }
        __syncthreads();
        #pragma unroll
        for (int kk = 0; kk < 64; kk += 32) {
            bf16x8 af[4], bfr[4];
            #pragma unroll
            for (int m = 0; m < 4; m++)
                af[m] = *reinterpret_cast<const bf16x8*>(&As[(wr * 64 + m * 16 + fr) * 64 + kk + fq * 8]);
            #pragma unroll
            for (int n = 0; n < 4; n++)
                bfr[n] = *reinterpret_cast<const bf16x8*>(&Bs[(wc * 64 + n * 16 + fr) * 64 + kk + fq * 8]);
            #pragma unroll
            for (int m = 0; m < 4; m++)
                #pragma unroll
                for (int n = 0; n < 4; n++)
                    acc[m][n] = __builtin_amdgcn_mfma_f32_16x16x32_bf16(af[m], bfr[n], acc[m][n], 0, 0, 0);
        }
        __syncthreads();
    }
    #pragma unroll
    for (int n = 0; n < 4; n++) {
        int col = bn + wc * 64 + n * 16 + fr;
        float bc = bias[col];
        #pragma unroll
        for (int m = 0; m < 4; m++) {
            #pragma unroll
            for (int r = 0; r < 4; r++) {
                size_t row = bm + wr * 64 + m * 16 + fq * 4 + r;
                float v = acc[m][n][r] + bc;
                if (OUT_BF16) {
                    __hip_bfloat16 hv = __float2bfloat16(v);
                    ((ushort*)Cout)[row * Ndim + col] = *(const ushort*)&hv;
                } else {
                    ((float*)Cout)[row * Ndim + col] = v;
                }
            }
        }
    }
}

// ---------------------------------------------------------------- MFMA attention
// One block per (b,kc,h), 512 threads = 8 waves; wave w owns query rows 32w..32w+31.
// Swapped QK^T: S'[j][i] = K·Q^T so each lane holds a full j-row for one query i.
// C/D layout (32x32): col = lane&31, row = (r&3) + 8*(r>>2) + 4*(lane>>5).
__global__ __launch_bounds__(512, 2) void attn_kernel(const ushort* __restrict__ qkv,
                                                      const int* __restrict__ member_idx,
                                                      const float* __restrict__ pos,
                                                      const float* __restrict__ w_pos,
                                                      const unsigned* __restrict__ pmax_u,
                                                      ushort* __restrict__ feat2) {
    const int h = blockIdx.x, kc = blockIdx.y, b = blockIdx.z;
    __shared__ ushort Ks[M_ * 16];        // 8 KB  row-major [256][16]
    __shared__ ushort Vt[64 * VSTR];      // 32.5 KB transposed V [c][j], stride 260
    __shared__ float  SpA[M_];            // bias reordered to crow order
    __shared__ int    Idx[M_];
    __shared__ float  dinvS[8 * 32];

    const int t  = threadIdx.x;
    const int w  = t >> 6, l = t & 63;
    const int hi = l >> 5, ln = l & 31;
    const int* mi = member_idx + (((size_t)b * H_ + h) * K_ + kc) * M_;
    const size_t rowbase = (size_t)b * N_;
    const float scale = 0.17677669529663687f;   // (C/H)^-0.5 = 1/sqrt(32)

    // ---- stage bias + Idx (crow-reordered so softmax reads are consecutive broadcasts)
    if (t < M_) {
        int n = mi[t];
        Idx[t] = n;
        float inv0 = 1.f / __uint_as_float(pmax_u[0]);
        float inv1 = 1.f / __uint_as_float(pmax_u[1]);
        float sp = pos[(rowbase + n) * 2 + 0] * inv0 * w_pos[h * 2 + 0]
                 + pos[(rowbase + n) * 2 + 1] * inv1 * w_pos[h * 2 + 1];
        int jj = t & 31, jt = t >> 5;
        int r  = (jj & 3) | ((jj >> 3) << 2);
        int hb = (jj >> 2) & 1;
        SpA[jt * 32 + hb * 16 + r] = sp;
    }
    // ---- stage K rows via global_load_lds (per-lane gather source, linear LDS dest)
    {
        int row = t >> 1, half = t & 1;
        int n = mi[row];
        load_lds_16B(qkv + (rowbase + n) * QKVD + h * 96 + 16 + half * 8, &Ks[t * 8]);
    }
    // ---- stage V transposed: thread = (row-pair u, c-quarter cq); pack 2 rows per b32 write
    {
        int u = t >> 2, cq = t & 3;
        int n0 = mi[2 * u], n1 = mi[2 * u + 1];
        const ushort* s0 = qkv + (rowbase + n0) * QKVD + h * 96 + 32 + cq * 16;
        const ushort* s1 = qkv + (rowbase + n1) * QKVD + h * 96 + 32 + cq * 16;
        ushort8v v0a = *(const ushort8v*)s0;
        ushort8v v0b = *(const ushort8v*)(s0 + 8);
        ushort8v v1a = *(const ushort8v*)s1;
        ushort8v v1b = *(const ushort8v*)(s1 + 8);
        #pragma unroll
        for (int i = 0; i < 8; i++) {
            int c0 = cq * 16 + i, c1 = cq * 16 + 8 + i;
            *(unsigned*)&Vt[c0 * VSTR + 2 * u] = (unsigned)(ushort)v0a[i] | ((unsigned)(ushort)v1a[i] << 16);
            *(unsigned*)&Vt[c1 * VSTR + 2 * u] = (unsigned)(ushort)v0b[i] | ((unsigned)(ushort)v1b[i] << 16);
        }
    }
    __syncthreads();

    // ---- Q B-frag direct from global: lane needs Q[i=32w+ln][8*hi..+8]
    const int iq = 32 * w + ln;
    const int nq = Idx[iq];
    bf16x8 qf = *(const bf16x8*)(qkv + (rowbase + nq) * QKVD + h * 96 + hi * 8);

    // ---- QK^T: 8 j-tiles of 32x32
    f32x16 zero16;
    #pragma unroll
    for (int i = 0; i < 16; i++) zero16[i] = 0.f;
    f32x16 sac[8];
    #pragma unroll
    for (int jt = 0; jt < 8; jt++) {
        bf16x8 kf = *(const bf16x8*)&Ks[(32 * jt + ln) * 16 + hi * 8];
        sac[jt] = __builtin_amdgcn_mfma_f32_32x32x16_bf16(kf, qf, zero16, 0, 0, 0);
    }

    // ---- softmax (lane-local over 128 regs + one cross-half exchange)
    float mx = -3.0e38f;
    #pragma unroll
    for (int jt = 0; jt < 8; jt++) {
        f32x4 bia[4];
        #pragma unroll
        for (int q4 = 0; q4 < 4; q4++)
            bia[q4] = *(const f32x4*)&SpA[jt * 32 + hi * 16 + q4 * 4];
        #pragma unroll
        for (int r = 0; r < 16; r++) {
            float v = fmaf(sac[jt][r], scale, bia[r >> 2][r & 3]);
            sac[jt][r] = v;
            mx = fmaxf(mx, v);
        }
    }
    mx = fmaxf(mx, __shfl_xor(mx, 32));
    float sum = 0.f;
    #pragma unroll
    for (int jt = 0; jt < 8; jt++)
        #pragma unroll
        for (int r = 0; r < 16; r++) {
            float p = __expf(sac[jt][r] - mx);
            sac[jt][r] = p;
            sum += p;
        }
    sum += __shfl_xor(sum, 32);
    float inv = 1.f / sum;
    if (hi == 0) dinvS[w * 32 + ln] = inv;

    // ---- PV: O[i][c] = sum_j P[j][i] V[j][c]; A-frag built in-register via cvt_pk+permlane
    f32x16 oa0 = zero16, oa1 = zero16;
    #pragma unroll
    for (int g = 0; g < 16; g++) {
        const int jt = g >> 1, hf = (g & 1) * 8;
        unsigned a0 = cvtpk_bf16(sac[jt][hf + 0], sac[jt][hf + 1]);
        unsigned a1 = cvtpk_bf16(sac[jt][hf + 2], sac[jt][hf + 3]);
        unsigned b0 = cvtpk_bf16(sac[jt][hf + 4], sac[jt][hf + 5]);
        unsigned b1 = cvtpk_bf16(sac[jt][hf + 6], sac[jt][hf + 7]);
        asm("v_permlane32_swap_b32 %0, %1" : "+v"(a0), "+v"(b0));
        asm("v_permlane32_swap_b32 %0, %1" : "+v"(a1), "+v"(b1));
        union { unsigned u[4]; bf16x8 v; } pa;
        pa.u[0] = a0; pa.u[1] = a1; pa.u[2] = b0; pa.u[3] = b1;
        union { ushort4v h[2]; bf16x8 v; } vf0, vf1;
        vf0.h[0] = *(const ushort4v*)&Vt[ln * VSTR + g * 16 + hi * 8];
        vf0.h[1] = *(const ushort4v*)&Vt[ln * VSTR + g * 16 + hi * 8 + 4];
        vf1.h[0] = *(const ushort4v*)&Vt[(ln + 32) * VSTR + g * 16 + hi * 8];
        vf1.h[1] = *(const ushort4v*)&Vt[(ln + 32) * VSTR + g * 16 + hi * 8 + 4];
        oa0 = __builtin_amdgcn_mfma_f32_32x32x16_bf16(pa.v, vf0.v, oa0, 0, 0, 0);
        oa1 = __builtin_amdgcn_mfma_f32_32x32x16_bf16(pa.v, vf1.v, oa1, 0, 0, 0);
    }

    // ---- epilogue: lane holds O[i=crow(r,hi)][c=ln(+32)]; scatter bf16 rows
    #pragma unroll
    for (int r = 0; r < 16; r++) {
        int crow = (r & 3) + 8 * (r >> 2) + 4 * hi;
        float dv = dinvS[w * 32 + crow];
        int ni = Idx[32 * w + crow];
        __hip_bfloat16 o0 = __float2bfloat16(oa0[r] * dv);
        __hip_bfloat16 o1 = __float2bfloat16(oa1[r] * dv);
        ushort* dst = feat2 + (rowbase + ni) * F2D + h * 64 + ln;
        dst[0]  = *(const ushort*)&o0;
        dst[32] = *(const ushort*)&o1;
    }
}

// ---------------------------------------------------------------- launch
extern "C" void kernel_launch(void* const* d_in, const int* in_sizes, int n_in,
                              void* d_out, int out_size, void* d_ws, size_t ws_size,
                              hipStream_t stream) {
    const float* pos    = (const float*)d_in[0];
    const float* feat   = (const float*)d_in[1];
    const int*   midx   = (const int*)  d_in[2];
    const float* w_qkv  = (const float*)d_in[3];
    const float* b_qkv  = (const float*)d_in[4];
    const float* w_pos  = (const float*)d_in[5];
    const float* b_pos  = (const float*)d_in[6];  (void)b_pos; // cancels in softmax
    const float* w_proj = (const float*)d_in[7];
    const float* b_proj = (const float*)d_in[8];
    float* out = (float*)d_out;

    // workspace: [pmax 256B | qkv bf16 75.5MB | wproj_bf16 0.6MB |
    //             REGION: {feat_bf16 25.2MB + wqkv_bf16 0.9MB} reused as feat2 50.3MB]
    char* ws = (char*)d_ws;
    unsigned* pmax  = (unsigned*)ws;
    ushort*   qkv   = (ushort*)(ws + 256);
    ushort*   wproj = (ushort*)(ws + 256 + 75497472);
    char*     region = ws + 256 + 75497472 + 589824;
    ushort*   featb = (ushort*)region;
    ushort*   wqkvb = (ushort*)(region + 25165824);
    ushort*   feat2 = (ushort*)region;   // overwrites featb/wqkvb after gemm_qkv

    hipMemsetAsync(pmax, 0, 8, stream);  // ws is NOT re-poisoned between replays
    posmax_kernel<<<64, 256, 0, stream>>>(pos, pmax);
    cast_kernel<<<(BN_ * C_ / 4 + 255) / 256, 256, 0, stream>>>(feat, featb, BN_ * C_ / 4);
    cast_kernel<<<(QKVD * C_ / 4 + 255) / 256, 256, 0, stream>>>(w_qkv, wqkvb, QKVD * C_ / 4);
    cast_kernel<<<(C_ * F2D / 4 + 255) / 256, 256, 0, stream>>>(w_proj, wproj, C_ * F2D / 4);
    // XCD-swizzled 1-D grids: 8 * 32 * (Ndim/128) blocks
    gemm_mfma<384, QKVD, true><<<8 * 32 * (QKVD / 128), 256, 0, stream>>>(featb, wqkvb, b_qkv, qkv);
    attn_kernel<<<dim3(H_, K_, B_), 512, 0, stream>>>(qkv, midx, pos, w_pos, pmax, feat2);
    gemm_mfma<768, C_, false><<<8 * 32 * (C_ / 128), 256, 0, stream>>>(feat2, wproj, b_proj, out);
}